// Round 5
// baseline (214.759 us; speedup 1.0000x reference)
//
#include <hip/hip_runtime.h>
#include <hip/hip_fp16.h>
#include <math.h>

#define NN 30000
#define KK 32
#define FF 256
#define DD 128

__device__ __forceinline__ float seluf(float x) {
    const float scale = 1.0507009873554804934193349852946f;
    const float alpha = 1.6732632423543772848170429916717f;
    return x > 0.f ? scale * x : scale * alpha * expm1f(x);
}

__device__ __forceinline__ float waveReduceSum(float v) {
#pragma unroll
    for (int m = 1; m < 64; m <<= 1) v += __shfl_xor(v, m, 64);
    return v;
}

// reduce across the 32 lanes of a half-wave (xor masks < 32 never cross halves)
__device__ __forceinline__ float halfReduceSum(float v) {
#pragma unroll
    for (int m = 1; m < 32; m <<= 1) v += __shfl_xor(v, m, 64);
    return v;
}

// -------- kernel 0: Mpad[127][128] = zero-padded M (aligned float4 reads) --
__global__ __launch_bounds__(256) void k_padM(
    const float* __restrict__ M, float* __restrict__ Mpad)
{
    const int idx = blockIdx.x * 256 + threadIdx.x;   // 0 .. 16255
    if (idx < 127 * 128) {
        const int f = idx >> 7, c = idx & 127;
        Mpad[idx] = (c < 127) ? M[f * 127 + c] : 0.f;
    }
}

// -------- kernel 1: h = normalize(exp_map_zero(selu(x @ W + b))) -----------
// 16 rows/block. Thread (cc=t&31, rg=t>>5) owns rows {rg, rg+8} x cols
// {4cc..4cc+3}. x tile in LDS (stride 260 -> rg groups on distinct banks);
// W read directly from global (L2-hot, 128 KB). ONE barrier total.
__global__ __launch_bounds__(256) void k_lin_exp(
    const float* __restrict__ x, const float* __restrict__ W,
    const float* __restrict__ b, float* __restrict__ h)
{
    __shared__ __align__(16) float xs[16 * 260];   // 16.6 KB, padded
    const int tid = threadIdx.x;
    const int blockRow = blockIdx.x * 16;

    const float4* xg = (const float4*)(x + (size_t)blockRow * FF);
    float4* xs4 = (float4*)xs;
#pragma unroll
    for (int i = 0; i < 4; ++i) {
        const int idx = i * 256 + tid;          // 0..1023
        const int row = idx >> 6, f4 = idx & 63;
        xs4[row * 65 + f4] = xg[idx];
    }
    __syncthreads();

    const int cc = tid & 31;
    const int rg = tid >> 5;
    const float4* Wg = (const float4*)W;        // [f][32 float4]
    float4 acc0 = {0.f, 0.f, 0.f, 0.f}, acc1 = {0.f, 0.f, 0.f, 0.f};

#pragma unroll 4
    for (int fq = 0; fq < 64; ++fq) {           // 4 f per iter
        const float4 xa = xs4[rg * 65 + fq];
        const float4 xb = xs4[(rg + 8) * 65 + fq];
        const float4 w0 = Wg[(4 * fq + 0) * 32 + cc];
        const float4 w1 = Wg[(4 * fq + 1) * 32 + cc];
        const float4 w2 = Wg[(4 * fq + 2) * 32 + cc];
        const float4 w3 = Wg[(4 * fq + 3) * 32 + cc];
        acc0.x = fmaf(xa.x, w0.x, acc0.x); acc0.y = fmaf(xa.x, w0.y, acc0.y);
        acc0.z = fmaf(xa.x, w0.z, acc0.z); acc0.w = fmaf(xa.x, w0.w, acc0.w);
        acc1.x = fmaf(xb.x, w0.x, acc1.x); acc1.y = fmaf(xb.x, w0.y, acc1.y);
        acc1.z = fmaf(xb.x, w0.z, acc1.z); acc1.w = fmaf(xb.x, w0.w, acc1.w);
        acc0.x = fmaf(xa.y, w1.x, acc0.x); acc0.y = fmaf(xa.y, w1.y, acc0.y);
        acc0.z = fmaf(xa.y, w1.z, acc0.z); acc0.w = fmaf(xa.y, w1.w, acc0.w);
        acc1.x = fmaf(xb.y, w1.x, acc1.x); acc1.y = fmaf(xb.y, w1.y, acc1.y);
        acc1.z = fmaf(xb.y, w1.z, acc1.z); acc1.w = fmaf(xb.y, w1.w, acc1.w);
        acc0.x = fmaf(xa.z, w2.x, acc0.x); acc0.y = fmaf(xa.z, w2.y, acc0.y);
        acc0.z = fmaf(xa.z, w2.z, acc0.z); acc0.w = fmaf(xa.z, w2.w, acc0.w);
        acc1.x = fmaf(xb.z, w2.x, acc1.x); acc1.y = fmaf(xb.z, w2.y, acc1.y);
        acc1.z = fmaf(xb.z, w2.z, acc1.z); acc1.w = fmaf(xb.z, w2.w, acc1.w);
        acc0.x = fmaf(xa.w, w3.x, acc0.x); acc0.y = fmaf(xa.w, w3.y, acc0.y);
        acc0.z = fmaf(xa.w, w3.z, acc0.z); acc0.w = fmaf(xa.w, w3.w, acc0.w);
        acc1.x = fmaf(xb.w, w3.x, acc1.x); acc1.y = fmaf(xb.w, w3.y, acc1.y);
        acc1.z = fmaf(xb.w, w3.z, acc1.z); acc1.w = fmaf(xb.w, w3.w, acc1.w);
    }

    const float4 bias = *(const float4*)(b + 4 * cc);
    float4 accs[2] = {acc0, acc1};
#pragma unroll
    for (int r = 0; r < 2; ++r) {
        const int row = blockRow + rg + 8 * r;
        float4 v;
        v.x = seluf(accs[r].x + bias.x);
        v.y = seluf(accs[r].y + bias.y);
        v.z = seluf(accs[r].z + bias.z);
        v.w = seluf(accs[r].w + bias.w);
        float part = (cc ? v.x * v.x : 0.f) + v.y * v.y + v.z * v.z + v.w * v.w;
        const float ldv = halfReduceSum(part);
        const float nd = sqrtf(fmaxf(ldv + 1e-9f, 1e-10f));
        const float t  = fminf(nd, 1.0f);
        const float sc = sinhf(t) / nd;
        const float tm = sqrtf(1.f + sc * sc * ldv);
        float4 o;
        o.x = cc ? sc * v.x : tm;
        o.y = sc * v.y;
        o.z = sc * v.z;
        o.w = sc * v.w;
        *(float4*)(h + (size_t)row * DD + 4 * cc) = o;
    }
}

// -------- kernel 2: fp16 gather table = aux(h @ blockdiag(1,Mpad)) ---------
// Same skeleton: h tile in LDS (stride 132), Mpad from global (L2-hot 64 KB).
// Thread's cols c' = 4cc..4cc+3 (Mpad col 127 is zero pad -> acc.w=0 for
// cc==31, store masked). table[row][0]=f-header, [d=c'+1]=Klein coord.
__global__ __launch_bounds__(256) void k_msg_aux(
    const float* __restrict__ h, const float* __restrict__ Mpad,
    __half* __restrict__ table)
{
    __shared__ __align__(16) float xs[16 * 132];   // 8.4 KB, padded
    const int tid = threadIdx.x;
    const int blockRow = blockIdx.x * 16;

    const float4* hg = (const float4*)(h + (size_t)blockRow * DD);
    float4* xs4 = (float4*)xs;
#pragma unroll
    for (int i = 0; i < 2; ++i) {
        const int idx = i * 256 + tid;          // 0..511
        const int row = idx >> 5, f4 = idx & 31;
        xs4[row * 33 + f4] = hg[idx];
    }
    __syncthreads();

    const int cc = tid & 31;
    const int rg = tid >> 5;
    const float4* Mg = (const float4*)Mpad;     // [127][32 float4]
    float4 acc0 = {0.f, 0.f, 0.f, 0.f}, acc1 = {0.f, 0.f, 0.f, 0.f};

#pragma unroll 4
    for (int f = 1; f < DD; ++f) {
        const float xa = xs[rg * 132 + f];
        const float xb = xs[(rg + 8) * 132 + f];
        const float4 m4 = Mg[(f - 1) * 32 + cc];
        acc0.x = fmaf(xa, m4.x, acc0.x); acc0.y = fmaf(xa, m4.y, acc0.y);
        acc0.z = fmaf(xa, m4.z, acc0.z); acc0.w = fmaf(xa, m4.w, acc0.w);
        acc1.x = fmaf(xb, m4.x, acc1.x); acc1.y = fmaf(xb, m4.y, acc1.y);
        acc1.z = fmaf(xb, m4.z, acc1.z); acc1.w = fmaf(xb, m4.w, acc1.w);
    }

    float4 accs[2] = {acc0, acc1};
#pragma unroll
    for (int r = 0; r < 2; ++r) {
        const int lrow = rg + 8 * r;
        const int row = blockRow + lrow;
        const float rn = 1.f / xs[lrow * 132];   // 1 / time coord
        float4 k4;
        k4.x = accs[r].x * rn;
        k4.y = accs[r].y * rn;
        k4.z = accs[r].z * rn;
        k4.w = accs[r].w * rn;                   // cc==31 -> zero pad col
        float part = k4.x * k4.x + k4.y * k4.y + k4.z * k4.z + k4.w * k4.w;
        float kn = halfReduceSum(part);
        kn = fminf(fmaxf(kn, 0.f), 0.9f);
        const float fh = 1.f / sqrtf(1.f - kn);
        __half* trow = table + (size_t)row * DD;
        const int d0 = 1 + 4 * cc;
        trow[d0]     = __float2half(k4.x);
        trow[d0 + 1] = __float2half(k4.y);
        trow[d0 + 2] = __float2half(k4.z);
        if (cc < 31) trow[d0 + 3] = __float2half(k4.w);
        if (cc == 0) trow[0] = __float2half(fh);
    }
}

// -------- kernel 3: gather + weighted mean + activation + normalize --------
__global__ __launch_bounds__(256) void k_layer(
    const __half* __restrict__ table, const int* __restrict__ adj,
    const float* __restrict__ w, float* __restrict__ out)
{
    const int wave = threadIdx.x >> 6;
    const int lane = threadIdx.x & 63;
    const int node = blockIdx.x * 4 + wave;

    const int   av = adj[node * KK + (lane & 31)];
    const float wv = w[node * KK + (lane & 31)];
    const float f  = __half2float(table[(size_t)av * DD]);
    const float lam = wv * f;
    float ls = lam;
#pragma unroll
    for (int m = 1; m < 32; m <<= 1) ls += __shfl_xor(ls, m, 64);

    float km0 = 0.f, km1 = 0.f;
#pragma unroll 8
    for (int j = 0; j < KK; ++j) {
        const int   idx = __shfl(av, j, 64);
        const float cj  = __shfl(lam, j, 64);
        const __half2 hh = *(const __half2*)(table + (size_t)idx * DD + lane * 2);
        const float2 v = __half22float2(hh);
        km0 = fmaf(cj, v.x, km0);   // lane0.x holds f-header, masked below
        km1 = fmaf(cj, v.y, km1);
    }
    const float rl = 1.f / ls;
    const float m0 = km0 * rl;
    const float m1 = km1 * rl;
    float c2 = (lane ? m0 * m0 : 0.f) + m1 * m1;
    const float kn2 = fminf(waveReduceSum(c2), 0.9f);
    const float invs = 1.f / sqrtf(1.f - kn2);
    const float pd = invs + 1.f;
    const float p0 = lane ? seluf(m0 * invs / pd) : 0.f;
    const float p1 = seluf(m1 * invs / pd);
    float pc = p0 * p0 + p1 * p1;
    const float pn = waveReduceSum(pc);
    const float rdn = 1.f / (1.f - pn + 1e-6f);
    const float tm = sqrtf(1.f + 4.f * pn * rdn * rdn);
    float2 o;
    o.x = lane ? 2.f * p0 * rdn : tm;
    o.y = 2.f * p1 * rdn;
    *(float2*)(out + (size_t)node * DD + lane * 2) = o;
}

extern "C" void kernel_launch(void* const* d_in, const int* in_sizes, int n_in,
                              void* d_out, int out_size, void* d_ws, size_t ws_size,
                              hipStream_t stream) {
    const float* x     = (const float*)d_in[0];
    const int*   adj   = (const int*)d_in[1];
    const float* w     = (const float*)d_in[2];
    const float* lin_W = (const float*)d_in[3];
    const float* lin_b = (const float*)d_in[4];
    const float* M     = (const float*)d_in[5];
    float*  h     = (float*)d_out;                             // N*D fp32
    __half* table = (__half*)d_ws;                             // 7.68 MB
    float*  Mpad  = (float*)((char*)d_ws + (size_t)NN * DD * 2); // 64 KB

    k_padM<<<(127 * 128 + 255) / 256, 256, 0, stream>>>(M, Mpad);
    k_lin_exp<<<NN / 16, 256, 0, stream>>>(x, lin_W, lin_b, h);
    // layer 0
    k_msg_aux<<<NN / 16, 256, 0, stream>>>(h, Mpad, table);
    k_layer<<<NN / 4, 256, 0, stream>>>(table, adj, w, h);
    // layer 1
    k_msg_aux<<<NN / 16, 256, 0, stream>>>(h, Mpad, table);
    k_layer<<<NN / 4, 256, 0, stream>>>(table, adj, w, h);
}

// Round 6
// 154.514 us; speedup vs baseline: 1.3899x; 1.3899x over previous
//
#include <hip/hip_runtime.h>
#include <hip/hip_fp16.h>
#include <math.h>

#define NN 30000
#define KK 32
#define FF 256
#define DD 128
#define GBLK ((NN + 63) / 64)

typedef _Float16 f16x8 __attribute__((ext_vector_type(8)));
typedef float f32x4v __attribute__((ext_vector_type(4)));

__device__ __forceinline__ float seluf(float x) {
    const float scale = 1.0507009873554804934193349852946f;
    const float alpha = 1.6732632423543772848170429916717f;
    return x > 0.f ? scale * x : scale * alpha * expm1f(x);
}

__device__ __forceinline__ float waveReduceSum(float v) {
#pragma unroll
    for (int m = 1; m < 64; m <<= 1) v += __shfl_xor(v, m, 64);
    return v;
}

// -------- kernel 0: transposed f16 hi/lo weight tables ---------------------
// Wt[n][k] = W[k][n] (128x256); Lt[c][k] = lw[k][c] (128x128, lw=blkdiag(1,M))
__global__ __launch_bounds__(256) void k_prep(
    const float* __restrict__ W, const float* __restrict__ M,
    _Float16* __restrict__ Wt_hi, _Float16* __restrict__ Wt_lo,
    _Float16* __restrict__ Lt_hi, _Float16* __restrict__ Lt_lo)
{
    const int b = blockIdx.x, t = threadIdx.x;
    if (b < 128) {
        const float v = W[t * DD + b];
        const _Float16 hi = (_Float16)v;
        Wt_hi[b * FF + t] = hi;
        Wt_lo[b * FF + t] = (_Float16)(v - (float)hi);
    } else if (t < 128) {
        const int c = b - 128, k = t;
        const float v = (k == 0 && c == 0) ? 1.f
                      : ((k >= 1 && c >= 1) ? M[(k - 1) * 127 + (c - 1)] : 0.f);
        const _Float16 hi = (_Float16)v;
        Lt_hi[c * DD + k] = hi;
        Lt_lo[c * DD + k] = (_Float16)(v - (float)hi);
    }
}

// -------- kernel 1: h = normalize(exp_map_zero(selu(x @ W + b))) -----------
// MFMA 16x16x32_f16, 3-term hi/lo split. Wave = 16 rows; block = 4 waves.
__global__ __launch_bounds__(256) void k_lin_exp(
    const float* __restrict__ x,
    const _Float16* __restrict__ Wt_hi, const _Float16* __restrict__ Wt_lo,
    const float* __restrict__ b, float* __restrict__ h)
{
    const int wave = threadIdx.x >> 6;
    const int lane = threadIdx.x & 63;
    const int g    = lane >> 4;       // k-group / row-quad group
    const int c16  = lane & 15;       // tile col (and A-row this lane loads)
    const int baseRow = blockIdx.x * 64 + wave * 16;
    const int arow = baseRow + c16;
    const bool rowOK = arow < NN;

    f32x4v acc[8];
#pragma unroll
    for (int n = 0; n < 8; ++n) acc[n] = f32x4v{0.f, 0.f, 0.f, 0.f};

#pragma unroll
    for (int ks = 0; ks < 8; ++ks) {
        f16x8 ahi, alo;
        if (rowOK) {
            const float4 f0 = *(const float4*)(x + (size_t)arow * FF + ks * 32 + g * 8);
            const float4 f1 = *(const float4*)(x + (size_t)arow * FF + ks * 32 + g * 8 + 4);
            const float fv[8] = {f0.x, f0.y, f0.z, f0.w, f1.x, f1.y, f1.z, f1.w};
#pragma unroll
            for (int j = 0; j < 8; ++j) {
                ahi[j] = (_Float16)fv[j];
                alo[j] = (_Float16)(fv[j] - (float)ahi[j]);
            }
        } else {
#pragma unroll
            for (int j = 0; j < 8; ++j) { ahi[j] = (_Float16)0.f; alo[j] = (_Float16)0.f; }
        }
#pragma unroll
        for (int n = 0; n < 8; ++n) {
            const size_t boff = (size_t)(n * 16 + c16) * FF + ks * 32 + g * 8;
            const f16x8 bhi = *(const f16x8*)(Wt_hi + boff);
            const f16x8 blo = *(const f16x8*)(Wt_lo + boff);
            acc[n] = __builtin_amdgcn_mfma_f32_16x16x32_f16(ahi, bhi, acc[n], 0, 0, 0);
            acc[n] = __builtin_amdgcn_mfma_f32_16x16x32_f16(alo, bhi, acc[n], 0, 0, 0);
            acc[n] = __builtin_amdgcn_mfma_f32_16x16x32_f16(ahi, blo, acc[n], 0, 0, 0);
        }
    }

    float bias[8];
#pragma unroll
    for (int n = 0; n < 8; ++n) bias[n] = b[n * 16 + c16];

#pragma unroll
    for (int r = 0; r < 4; ++r) {
        const int row = baseRow + 4 * g + r;
        float v[8];
        float part = 0.f;
#pragma unroll
        for (int n = 0; n < 8; ++n) {
            v[n] = seluf(acc[n][r] + bias[n]);
            float sq = v[n] * v[n];
            if (n == 0 && c16 == 0) sq = 0.f;   // exclude d=0 (time slot)
            part += sq;
        }
#pragma unroll
        for (int m = 1; m < 16; m <<= 1) part += __shfl_xor(part, m, 64);
        const float ldv = part;
        const float nd = sqrtf(fmaxf(ldv + 1e-9f, 1e-10f));
        const float t  = fminf(nd, 1.0f);
        const float sc = sinhf(t) / nd;
        const float tm = sqrtf(1.f + sc * sc * ldv);
        if (row < NN) {
#pragma unroll
            for (int n = 0; n < 8; ++n) {
                const float o = (n == 0 && c16 == 0) ? tm : sc * v[n];
                h[(size_t)row * DD + n * 16 + c16] = o;
            }
        }
    }
}

// -------- kernel 2: fp16 gather table = aux(h @ lw) via MFMA ---------------
// msg = h @ lw (D=A*B, A=h rows, B=Lt cols); then Klein + f-header epilogue.
__global__ __launch_bounds__(256) void k_msg_aux(
    const float* __restrict__ h,
    const _Float16* __restrict__ Lt_hi, const _Float16* __restrict__ Lt_lo,
    __half* __restrict__ table)
{
    const int wave = threadIdx.x >> 6;
    const int lane = threadIdx.x & 63;
    const int g    = lane >> 4;
    const int c16  = lane & 15;
    const int baseRow = blockIdx.x * 64 + wave * 16;
    const int arow = baseRow + c16;
    const bool rowOK = arow < NN;

    f32x4v acc[8];
#pragma unroll
    for (int n = 0; n < 8; ++n) acc[n] = f32x4v{0.f, 0.f, 0.f, 0.f};

#pragma unroll
    for (int ks = 0; ks < 4; ++ks) {
        f16x8 ahi, alo;
        if (rowOK) {
            const float4 f0 = *(const float4*)(h + (size_t)arow * DD + ks * 32 + g * 8);
            const float4 f1 = *(const float4*)(h + (size_t)arow * DD + ks * 32 + g * 8 + 4);
            const float fv[8] = {f0.x, f0.y, f0.z, f0.w, f1.x, f1.y, f1.z, f1.w};
#pragma unroll
            for (int j = 0; j < 8; ++j) {
                ahi[j] = (_Float16)fv[j];
                alo[j] = (_Float16)(fv[j] - (float)ahi[j]);
            }
        } else {
#pragma unroll
            for (int j = 0; j < 8; ++j) { ahi[j] = (_Float16)0.f; alo[j] = (_Float16)0.f; }
        }
#pragma unroll
        for (int n = 0; n < 8; ++n) {
            const size_t boff = (size_t)(n * 16 + c16) * DD + ks * 32 + g * 8;
            const f16x8 bhi = *(const f16x8*)(Lt_hi + boff);
            const f16x8 blo = *(const f16x8*)(Lt_lo + boff);
            acc[n] = __builtin_amdgcn_mfma_f32_16x16x32_f16(ahi, bhi, acc[n], 0, 0, 0);
            acc[n] = __builtin_amdgcn_mfma_f32_16x16x32_f16(alo, bhi, acc[n], 0, 0, 0);
            acc[n] = __builtin_amdgcn_mfma_f32_16x16x32_f16(ahi, blo, acc[n], 0, 0, 0);
        }
    }

    // time coordinate msg[row][0] lives at col 0 (lane g*16, n-tile 0)
    float rn_[4];
#pragma unroll
    for (int r = 0; r < 4; ++r) {
        const float m0 = __shfl(acc[0][r], lane & 48, 64);
        rn_[r] = 1.f / m0;
    }

#pragma unroll
    for (int r = 0; r < 4; ++r) {
        const int row = baseRow + 4 * g + r;
        float kk[8];
        float part = 0.f;
#pragma unroll
        for (int n = 0; n < 8; ++n) {
            kk[n] = acc[n][r] * rn_[r];
            float sq = kk[n] * kk[n];
            if (n == 0 && c16 == 0) sq = 0.f;   // d=0 is time, not a Klein coord
            part += sq;
        }
#pragma unroll
        for (int m = 1; m < 16; m <<= 1) part += __shfl_xor(part, m, 64);
        float kn = fminf(fmaxf(part, 0.f), 0.9f);
        const float fh = 1.f / sqrtf(1.f - kn);
        if (row < NN) {
#pragma unroll
            for (int n = 0; n < 8; ++n) {
                const float val = (n == 0 && c16 == 0) ? fh : kk[n];
                table[(size_t)row * DD + n * 16 + c16] = __float2half(val);
            }
        }
    }
}

// -------- kernel 3: gather + weighted mean + activation + normalize --------
__global__ __launch_bounds__(256) void k_layer(
    const __half* __restrict__ table, const int* __restrict__ adj,
    const float* __restrict__ w, float* __restrict__ out)
{
    const int wave = threadIdx.x >> 6;
    const int lane = threadIdx.x & 63;
    const int node = blockIdx.x * 4 + wave;

    const int   av = adj[node * KK + (lane & 31)];
    const float wv = w[node * KK + (lane & 31)];
    const float f  = __half2float(table[(size_t)av * DD]);
    const float lam = wv * f;
    float ls = lam;
#pragma unroll
    for (int m = 1; m < 32; m <<= 1) ls += __shfl_xor(ls, m, 64);

    float km0 = 0.f, km1 = 0.f;
#pragma unroll 8
    for (int j = 0; j < KK; ++j) {
        const int   idx = __shfl(av, j, 64);
        const float cj  = __shfl(lam, j, 64);
        const __half2 hh = *(const __half2*)(table + (size_t)idx * DD + lane * 2);
        const float2 v = __half22float2(hh);
        km0 = fmaf(cj, v.x, km0);   // lane0.x holds f-header, masked below
        km1 = fmaf(cj, v.y, km1);
    }
    const float rl = 1.f / ls;
    const float m0 = km0 * rl;
    const float m1 = km1 * rl;
    float c2 = (lane ? m0 * m0 : 0.f) + m1 * m1;
    const float kn2 = fminf(waveReduceSum(c2), 0.9f);
    const float invs = 1.f / sqrtf(1.f - kn2);
    const float pd = invs + 1.f;
    const float p0 = lane ? seluf(m0 * invs / pd) : 0.f;
    const float p1 = seluf(m1 * invs / pd);
    float pc = p0 * p0 + p1 * p1;
    const float pn = waveReduceSum(pc);
    const float rdn = 1.f / (1.f - pn + 1e-6f);
    const float tm = sqrtf(1.f + 4.f * pn * rdn * rdn);
    float2 o;
    o.x = lane ? 2.f * p0 * rdn : tm;
    o.y = 2.f * p1 * rdn;
    *(float2*)(out + (size_t)node * DD + lane * 2) = o;
}

extern "C" void kernel_launch(void* const* d_in, const int* in_sizes, int n_in,
                              void* d_out, int out_size, void* d_ws, size_t ws_size,
                              hipStream_t stream) {
    const float* x     = (const float*)d_in[0];
    const int*   adj   = (const int*)d_in[1];
    const float* w     = (const float*)d_in[2];
    const float* lin_W = (const float*)d_in[3];
    const float* lin_b = (const float*)d_in[4];
    const float* M     = (const float*)d_in[5];
    float*  h     = (float*)d_out;                 // N*D fp32 (ping)
    char*   ws    = (char*)d_ws;
    __half* table = (__half*)ws;                   // 7,680,000 B
    _Float16* Wt_hi = (_Float16*)(ws + 7680000);   // 65,536 B
    _Float16* Wt_lo = (_Float16*)(ws + 7745536);   // 65,536 B
    _Float16* Lt_hi = (_Float16*)(ws + 7811072);   // 32,768 B
    _Float16* Lt_lo = (_Float16*)(ws + 7843840);   // 32,768 B

    k_prep<<<256, 256, 0, stream>>>(lin_W, M, Wt_hi, Wt_lo, Lt_hi, Lt_lo);
    k_lin_exp<<<GBLK, 256, 0, stream>>>(x, Wt_hi, Wt_lo, lin_b, h);
    // layer 0
    k_msg_aux<<<GBLK, 256, 0, stream>>>(h, Lt_hi, Lt_lo, table);
    k_layer<<<NN / 4, 256, 0, stream>>>(table, adj, w, h);
    // layer 1
    k_msg_aux<<<GBLK, 256, 0, stream>>>(h, Lt_hi, Lt_lo, table);
    k_layer<<<NN / 4, 256, 0, stream>>>(table, adj, w, h);
}

// Round 7
// 132.819 us; speedup vs baseline: 1.6169x; 1.1633x over previous
//
#include <hip/hip_runtime.h>
#include <hip/hip_fp16.h>
#include <math.h>

#define NN 30000
#define KK 32
#define FF 256
#define DD 128
#define NB 938   // ceil(30000/32)

typedef _Float16 f16x8 __attribute__((ext_vector_type(8)));
typedef float f32x4v __attribute__((ext_vector_type(4)));

__device__ __forceinline__ float seluf(float x) {
    const float scale = 1.0507009873554804934193349852946f;
    const float alpha = 1.6732632423543772848170429916717f;
    return x > 0.f ? scale * x : scale * alpha * expm1f(x);
}

__device__ __forceinline__ float waveReduceSum(float v) {
#pragma unroll
    for (int m = 1; m < 64; m <<= 1) v += __shfl_xor(v, m, 64);
    return v;
}

// -------- kernel 0: transposed f16 weight tables ---------------------------
// Wt[n][k] = W[k][n] (128x256); Lt[c][k] = lw[k][c] (128x128, lw=blkdiag(1,M))
__global__ __launch_bounds__(256) void k_prep(
    const float* __restrict__ W, const float* __restrict__ M,
    _Float16* __restrict__ Wt, _Float16* __restrict__ Lt)
{
    const int b = blockIdx.x, t = threadIdx.x;
    if (b < 128) {
        Wt[b * FF + t] = (_Float16)W[t * DD + b];
    } else if (t < 128) {
        const int c = b - 128, k = t;
        const float v = (k == 0 && c == 0) ? 1.f
                      : ((k >= 1 && c >= 1) ? M[(k - 1) * 127 + (c - 1)] : 0.f);
        Lt[c * DD + k] = (_Float16)v;
    }
}

// -------- kernel 1: h = normalize(exp_map_zero(selu(x @ W + b))) -----------
// MFMA 16x16x32_f16, A hi/lo 2-term (exact A), B single f16.
// Block = 4 waves: waves {0,1} rows base..base+15 (cols 0-63 / 64-127),
// waves {2,3} rows base+16..base+31. All A loads hoisted.
__global__ __launch_bounds__(256) void k_lin_exp(
    const float* __restrict__ x, const _Float16* __restrict__ Wt,
    const float* __restrict__ b, float* __restrict__ h)
{
    __shared__ float red[4][16];
    const int wv_ = threadIdx.x >> 6;
    const int lane = threadIdx.x & 63;
    const int g = lane >> 4, c16 = lane & 15;
    const int baseRow = blockIdx.x * 32 + (wv_ >> 1) * 16;
    const int nb = (wv_ & 1) * 4;           // n-tile base (4 tiles = 64 cols)
    const int arow = baseRow + c16;
    const bool rowOK = arow < NN;

    float4 f[16];
    const float4* xp = (const float4*)(x + (size_t)arow * FF) + g * 2;
    if (rowOK) {
#pragma unroll
        for (int ks = 0; ks < 8; ++ks) {
            f[2 * ks]     = xp[ks * 8];
            f[2 * ks + 1] = xp[ks * 8 + 1];
        }
    } else {
#pragma unroll
        for (int i = 0; i < 16; ++i) f[i] = float4{0.f, 0.f, 0.f, 0.f};
    }
    f16x8 ahi[8], alo[8];
#pragma unroll
    for (int ks = 0; ks < 8; ++ks) {
        const float q[8] = {f[2 * ks].x, f[2 * ks].y, f[2 * ks].z, f[2 * ks].w,
                            f[2 * ks + 1].x, f[2 * ks + 1].y, f[2 * ks + 1].z, f[2 * ks + 1].w};
#pragma unroll
        for (int j = 0; j < 8; ++j) {
            ahi[ks][j] = (_Float16)q[j];
            alo[ks][j] = (_Float16)(q[j] - (float)ahi[ks][j]);
        }
    }

    f32x4v acc[4];
#pragma unroll
    for (int n = 0; n < 4; ++n) acc[n] = f32x4v{0.f, 0.f, 0.f, 0.f};
#pragma unroll
    for (int ks = 0; ks < 8; ++ks) {
#pragma unroll
        for (int n = 0; n < 4; ++n) {
            const f16x8 bh = *(const f16x8*)(Wt + (size_t)((nb + n) * 16 + c16) * FF + ks * 32 + g * 8);
            acc[n] = __builtin_amdgcn_mfma_f32_16x16x32_f16(ahi[ks], bh, acc[n], 0, 0, 0);
            acc[n] = __builtin_amdgcn_mfma_f32_16x16x32_f16(alo[ks], bh, acc[n], 0, 0, 0);
        }
    }

    float bias[4];
#pragma unroll
    for (int n = 0; n < 4; ++n) bias[n] = b[(nb + n) * 16 + c16];

    float vv[4][4];
#pragma unroll
    for (int r = 0; r < 4; ++r) {
        float part = 0.f;
#pragma unroll
        for (int n = 0; n < 4; ++n) {
            vv[r][n] = seluf(acc[n][r] + bias[n]);
            float sq = vv[r][n] * vv[r][n];
            if (nb == 0 && n == 0 && c16 == 0) sq = 0.f;   // exclude d=0
            part += sq;
        }
#pragma unroll
        for (int m = 1; m < 16; m <<= 1) part += __shfl_xor(part, m, 64);
        if (c16 == 0) red[wv_][4 * g + r] = part;
    }
    __syncthreads();
#pragma unroll
    for (int r = 0; r < 4; ++r) {
        const int row = baseRow + 4 * g + r;
        const float ldv = red[wv_][4 * g + r] + red[wv_ ^ 1][4 * g + r];
        const float nd = sqrtf(fmaxf(ldv + 1e-9f, 1e-10f));
        const float t  = fminf(nd, 1.0f);
        const float sc = sinhf(t) / nd;
        const float tm = sqrtf(1.f + sc * sc * ldv);
        if (row < NN) {
#pragma unroll
            for (int n = 0; n < 4; ++n) {
                const float o = (nb == 0 && n == 0 && c16 == 0) ? tm : sc * vv[r][n];
                h[(size_t)row * DD + (nb + n) * 16 + c16] = o;
            }
        }
    }
}

// -------- kernel 2: fp16 gather table = aux(h @ lw) via MFMA ---------------
// Same structure; kn reduced on raw acc^2 then scaled by rn^2 (one barrier).
__global__ __launch_bounds__(256) void k_msg_aux(
    const float* __restrict__ h, const _Float16* __restrict__ Lt,
    __half* __restrict__ table)
{
    __shared__ float red[4][16];
    __shared__ float m0s[2][16];
    const int wv_ = threadIdx.x >> 6;
    const int lane = threadIdx.x & 63;
    const int g = lane >> 4, c16 = lane & 15;
    const int baseRow = blockIdx.x * 32 + (wv_ >> 1) * 16;
    const int nb = (wv_ & 1) * 4;
    const int arow = baseRow + c16;
    const bool rowOK = arow < NN;

    float4 f[8];
    const float4* hp = (const float4*)(h + (size_t)arow * DD) + g * 2;
    if (rowOK) {
#pragma unroll
        for (int ks = 0; ks < 4; ++ks) {
            f[2 * ks]     = hp[ks * 8];
            f[2 * ks + 1] = hp[ks * 8 + 1];
        }
    } else {
#pragma unroll
        for (int i = 0; i < 8; ++i) f[i] = float4{0.f, 0.f, 0.f, 0.f};
    }
    f16x8 ahi[4], alo[4];
#pragma unroll
    for (int ks = 0; ks < 4; ++ks) {
        const float q[8] = {f[2 * ks].x, f[2 * ks].y, f[2 * ks].z, f[2 * ks].w,
                            f[2 * ks + 1].x, f[2 * ks + 1].y, f[2 * ks + 1].z, f[2 * ks + 1].w};
#pragma unroll
        for (int j = 0; j < 8; ++j) {
            ahi[ks][j] = (_Float16)q[j];
            alo[ks][j] = (_Float16)(q[j] - (float)ahi[ks][j]);
        }
    }

    f32x4v acc[4];
#pragma unroll
    for (int n = 0; n < 4; ++n) acc[n] = f32x4v{0.f, 0.f, 0.f, 0.f};
#pragma unroll
    for (int ks = 0; ks < 4; ++ks) {
#pragma unroll
        for (int n = 0; n < 4; ++n) {
            const f16x8 bh = *(const f16x8*)(Lt + (size_t)((nb + n) * 16 + c16) * DD + ks * 32 + g * 8);
            acc[n] = __builtin_amdgcn_mfma_f32_16x16x32_f16(ahi[ks], bh, acc[n], 0, 0, 0);
            acc[n] = __builtin_amdgcn_mfma_f32_16x16x32_f16(alo[ks], bh, acc[n], 0, 0, 0);
        }
    }

#pragma unroll
    for (int r = 0; r < 4; ++r) {
        float part = 0.f;
#pragma unroll
        for (int n = 0; n < 4; ++n) {
            float sq = acc[n][r] * acc[n][r];
            if (nb == 0 && n == 0 && c16 == 0) sq = 0.f;   // time slot
            part += sq;
        }
#pragma unroll
        for (int m = 1; m < 16; m <<= 1) part += __shfl_xor(part, m, 64);
        if (c16 == 0) red[wv_][4 * g + r] = part;
        if (nb == 0 && c16 == 0) m0s[wv_ >> 1][4 * g + r] = acc[0][r];
    }
    __syncthreads();
#pragma unroll
    for (int r = 0; r < 4; ++r) {
        const int row = baseRow + 4 * g + r;
        const float rn = 1.f / m0s[wv_ >> 1][4 * g + r];
        const float sum2 = red[wv_][4 * g + r] + red[wv_ ^ 1][4 * g + r];
        float kn = sum2 * rn * rn;
        kn = fminf(fmaxf(kn, 0.f), 0.9f);
        const float fh = 1.f / sqrtf(1.f - kn);
        if (row < NN) {
#pragma unroll
            for (int n = 0; n < 4; ++n) {
                const float val = (nb == 0 && n == 0 && c16 == 0) ? fh : acc[n][r] * rn;
                table[(size_t)row * DD + (nb + n) * 16 + c16] = __float2half(val);
            }
        }
    }
}

// -------- kernel 3: gather + weighted mean + activation + normalize --------
// one wave per node; all 32 row-gathers prefetched into registers.
__global__ __launch_bounds__(256) void k_layer(
    const __half* __restrict__ table, const int* __restrict__ adj,
    const float* __restrict__ w, float* __restrict__ out)
{
    const int wave = threadIdx.x >> 6;
    const int lane = threadIdx.x & 63;
    const int node = blockIdx.x * 4 + wave;

    const int   av = adj[node * KK + (lane & 31)];
    const float wv = w[node * KK + (lane & 31)];

    unsigned int vbits[32];
#pragma unroll
    for (int j = 0; j < KK; ++j) {
        const int idx = __shfl(av, j, 64);
        vbits[j] = *(const unsigned int*)(table + (size_t)idx * DD + lane * 2);
    }

    const float f  = __half2float(table[(size_t)av * DD]);
    const float lam = wv * f;
    float ls = lam;
#pragma unroll
    for (int m = 1; m < 32; m <<= 1) ls += __shfl_xor(ls, m, 64);

    float km0 = 0.f, km1 = 0.f;
#pragma unroll
    for (int j = 0; j < KK; ++j) {
        const float cj = __shfl(lam, j, 64);
        const __half2 hh = *(const __half2*)&vbits[j];
        const float2 v = __half22float2(hh);
        km0 = fmaf(cj, v.x, km0);   // lane0.x holds f-header, masked below
        km1 = fmaf(cj, v.y, km1);
    }
    const float rl = 1.f / ls;
    const float m0 = km0 * rl;
    const float m1 = km1 * rl;
    float c2 = (lane ? m0 * m0 : 0.f) + m1 * m1;
    const float kn2 = fminf(waveReduceSum(c2), 0.9f);
    const float invs = 1.f / sqrtf(1.f - kn2);
    const float pd = invs + 1.f;
    const float p0 = lane ? seluf(m0 * invs / pd) : 0.f;
    const float p1 = seluf(m1 * invs / pd);
    float pc = p0 * p0 + p1 * p1;
    const float pn = waveReduceSum(pc);
    const float rdn = 1.f / (1.f - pn + 1e-6f);
    const float tm = sqrtf(1.f + 4.f * pn * rdn * rdn);
    float2 o;
    o.x = lane ? 2.f * p0 * rdn : tm;
    o.y = 2.f * p1 * rdn;
    *(float2*)(out + (size_t)node * DD + lane * 2) = o;
}

extern "C" void kernel_launch(void* const* d_in, const int* in_sizes, int n_in,
                              void* d_out, int out_size, void* d_ws, size_t ws_size,
                              hipStream_t stream) {
    const float* x     = (const float*)d_in[0];
    const int*   adj   = (const int*)d_in[1];
    const float* w     = (const float*)d_in[2];
    const float* lin_W = (const float*)d_in[3];
    const float* lin_b = (const float*)d_in[4];
    const float* M     = (const float*)d_in[5];
    float*  h     = (float*)d_out;                 // N*D fp32 (ping)
    char*   ws    = (char*)d_ws;
    __half* table = (__half*)ws;                   // 7,680,000 B
    _Float16* Wt  = (_Float16*)(ws + 7680000);     // 65,536 B
    _Float16* Lt  = (_Float16*)(ws + 7745536);     // 32,768 B

    k_prep<<<256, 256, 0, stream>>>(lin_W, M, Wt, Lt);
    k_lin_exp<<<NB, 256, 0, stream>>>(x, Wt, lin_b, h);
    // layer 0
    k_msg_aux<<<NB, 256, 0, stream>>>(h, Lt, table);
    k_layer<<<NN / 4, 256, 0, stream>>>(table, adj, w, h);
    // layer 1
    k_msg_aux<<<NB, 256, 0, stream>>>(h, Lt, table);
    k_layer<<<NN / 4, 256, 0, stream>>>(table, adj, w, h);
}